// Round 3
// baseline (659.193 us; speedup 1.0000x reference)
//
#include <hip/hip_runtime.h>
#include <float.h>

// VectorQuantizerEMA: ze (32,64,2048) f32, codebook (1024,64) f32
#define B_   32
#define D_   64
#define TP_  2048
#define K_   1024
#define N_   (B_ * TP_)          // 65536 rows
#define BETA_ 0.25f

// ws layout (float units):
//   [0,1024)    : nc2[k] = np-replicated f32 ||c_k||^2 (pairwise-8 sum)
//   [1024]      : commit-loss accumulator (float, atomic)
//   [1025]      : ambiguous-row count (unsigned, atomic)
//   [1088,2112) : histogram (unsigned, atomic)
//   [2112,...)  : ambiguous list, u32 entries: (row<<10)|guess
#define WS_SC2   0
#define WS_LOSS  1024
#define WS_CNT   1025
#define WS_HIST  1088
#define WS_LIST  2112
#define CAP_     16384

// ambiguity margin: grid rounding (2*ulp(64)=1.5e-5) + ref dot err (~2e-6)
// + our fine-pass err (~1e-6) << 2.5e-4. Expected flagged rows ~100.
#define MARGIN_  2.5e-4f

// ---------------- init: np-replicated ||c||^2, zero hist/loss/cnt -----------
__global__ void vq_init(const float* __restrict__ cb, float* __restrict__ ws) {
    int k = blockIdx.x * blockDim.x + threadIdx.x;
    if (k < K_) {
        const float* c = cb + (size_t)k * D_;
        // numpy pairwise-8: r[j]=p[j]; r[j]+=p[8i+j]; ((r0+r1)+(r2+r3))+((r4+r5)+(r6+r7))
        float r[8];
#pragma unroll
        for (int j = 0; j < 8; ++j) r[j] = c[j] * c[j];
#pragma unroll
        for (int i = 1; i < 8; ++i)
#pragma unroll
            for (int j = 0; j < 8; ++j) { float v = c[8 * i + j]; r[j] += v * v; }
        ws[WS_SC2 + k] = ((r[0] + r[1]) + (r[2] + r[3])) + ((r[4] + r[5]) + (r[6] + r[7]));
        reinterpret_cast<unsigned*>(ws + WS_HIST)[k] = 0u;
        if (k == 0) {
            ws[WS_LOSS] = 0.f;
            reinterpret_cast<unsigned*>(ws)[WS_CNT] = 0u;
        }
    }
}

// ---------------- main: fast f32 argmin + outputs + flag ambiguous ----------
__global__ __launch_bounds__(256) void vq_main(const float* __restrict__ ze,
                                               const float* __restrict__ cb,
                                               float* __restrict__ out,
                                               float* __restrict__ ws) {
    __shared__ unsigned lhist[K_];
    const int tid = threadIdx.x;
#pragma unroll
    for (int i = tid; i < K_; i += 256) lhist[i] = 0u;

    const int n  = blockIdx.x * 256 + tid;
    const int b  = n >> 11;
    const int tp = n & (TP_ - 1);

    const float* zp = ze + (size_t)b * D_ * TP_ + tp;
    float x[D_];
#pragma unroll
    for (int d = 0; d < D_; ++d) x[d] = zp[(size_t)d * TP_];

    const float4* cb4 = reinterpret_cast<const float4*>(cb);
    const float*  sc2 = ws + WS_SC2;

    float best  = 3.4e38f;
    float best2 = 3.4e38f;
    int   bidx  = 0;

    for (int k0 = 0; k0 < K_; k0 += 4) {
        const float4* p0 = cb4 + (size_t)(k0 + 0) * (D_ / 4);
        const float4* p1 = cb4 + (size_t)(k0 + 1) * (D_ / 4);
        const float4* p2 = cb4 + (size_t)(k0 + 2) * (D_ / 4);
        const float4* p3 = cb4 + (size_t)(k0 + 3) * (D_ / 4);
        float d0 = 0.f, d1 = 0.f, d2 = 0.f, d3 = 0.f;
#pragma unroll
        for (int j = 0; j < D_ / 4; ++j) {
            float4 a = p0[j], bb = p1[j], c = p2[j], dd = p3[j];
            d0 = fmaf(x[4 * j + 0], a.x, d0);
            d0 = fmaf(x[4 * j + 1], a.y, d0);
            d0 = fmaf(x[4 * j + 2], a.z, d0);
            d0 = fmaf(x[4 * j + 3], a.w, d0);
            d1 = fmaf(x[4 * j + 0], bb.x, d1);
            d1 = fmaf(x[4 * j + 1], bb.y, d1);
            d1 = fmaf(x[4 * j + 2], bb.z, d1);
            d1 = fmaf(x[4 * j + 3], bb.w, d1);
            d2 = fmaf(x[4 * j + 0], c.x, d2);
            d2 = fmaf(x[4 * j + 1], c.y, d2);
            d2 = fmaf(x[4 * j + 2], c.z, d2);
            d2 = fmaf(x[4 * j + 3], c.w, d2);
            d3 = fmaf(x[4 * j + 0], dd.x, d3);
            d3 = fmaf(x[4 * j + 1], dd.y, d3);
            d3 = fmaf(x[4 * j + 2], dd.z, d3);
            d3 = fmaf(x[4 * j + 3], dd.w, d3);
        }
        float v0 = sc2[k0 + 0] - 2.f * d0;
        float v1 = sc2[k0 + 1] - 2.f * d1;
        float v2 = sc2[k0 + 2] - 2.f * d2;
        float v3 = sc2[k0 + 3] - 2.f * d3;
        if (v0 < best) { best2 = best; best = v0; bidx = k0 + 0; } else if (v0 < best2) best2 = v0;
        if (v1 < best) { best2 = best; best = v1; bidx = k0 + 1; } else if (v1 < best2) best2 = v1;
        if (v2 < best) { best2 = best; best = v2; bidx = k0 + 2; } else if (v2 < best2) best2 = v2;
        if (v3 < best) { best2 = best; best = v3; bidx = k0 + 3; } else if (v3 < best2) best2 = v3;
    }

    // ambiguous vs the reference's coarse (+||x||^2) grid -> defer to fixup kernel
    if (best2 - best < MARGIN_) {
        unsigned slot = atomicAdd(reinterpret_cast<unsigned*>(ws) + WS_CNT, 1u);
        if (slot < CAP_)
            reinterpret_cast<unsigned*>(ws + WS_LIST)[slot] =
                ((unsigned)n << 10) | (unsigned)bidx;
    }

    __syncthreads();
    atomicAdd(&lhist[bidx], 1u);

    const float4* q4 = cb4 + (size_t)bidx * (D_ / 4);
    float* o0 = out + (size_t)b * D_ * TP_ + tp;
    float lsum = 0.f;
#pragma unroll
    for (int j = 0; j < D_ / 4; ++j) {
        float4 q = q4[j];
        float qv[4] = {q.x, q.y, q.z, q.w};
#pragma unroll
        for (int c = 0; c < 4; ++c) {
            int   d   = 4 * j + c;
            float zev = x[d];
            o0[(size_t)d * TP_] = qv[c];               // ze + (zq - ze) == zq
            float diff = zev - qv[c];
            lsum = fmaf(diff, diff, lsum);
        }
    }
    out[(size_t)N_ * D_ + n] = (float)bidx;

#pragma unroll
    for (int m = 32; m >= 1; m >>= 1) lsum += __shfl_xor(lsum, m, 64);
    if ((tid & 63) == 0) atomicAdd(ws + WS_LOSS, lsum);

    __syncthreads();
    unsigned* gh = reinterpret_cast<unsigned*>(ws + WS_HIST);
#pragma unroll
    for (int i = tid; i < K_; i += 256) {
        unsigned c = lhist[i];
        if (c) atomicAdd(&gh[i], c);
    }
}

// ---------------- fixup: replicate ref grid argmin for ambiguous rows -------
// one wave per row; lane handles 16 codes; first-index tie-break via packed min
__global__ __launch_bounds__(256) void vq_fix(const float* __restrict__ ze,
                                              const float* __restrict__ cb,
                                              float* __restrict__ out,
                                              float* __restrict__ ws) {
    const int lane = threadIdx.x & 63;
    const unsigned w = blockIdx.x * 4 + (threadIdx.x >> 6);   // wave id, 256 total
    unsigned cnt = reinterpret_cast<const unsigned*>(ws)[WS_CNT];
    if (cnt > CAP_) cnt = CAP_;
    const unsigned* list = reinterpret_cast<const unsigned*>(ws + WS_LIST);
    const float* sc2 = ws + WS_SC2;
    unsigned* gh = reinterpret_cast<unsigned*>(ws + WS_HIST);

    for (unsigned i = w; i < cnt; i += 256) {
        unsigned e = list[i];
        const int n     = (int)(e >> 10);
        const int guess = (int)(e & 1023u);
        const int b  = n >> 11;
        const int tp = n & (TP_ - 1);
        const float* zp = ze + (size_t)b * D_ * TP_ + tp;    // wave-uniform

        float xr[D_];
#pragma unroll
        for (int j = 0; j < D_; ++j) xr[j] = zp[(size_t)j * TP_];

        // np pairwise-8 ||x||^2 (bit-exact replication of np.sum(x*x, axis=1))
        float r[8];
#pragma unroll
        for (int j = 0; j < 8; ++j) r[j] = xr[j] * xr[j];
#pragma unroll
        for (int ii = 1; ii < 8; ++ii)
#pragma unroll
            for (int j = 0; j < 8; ++j) { float v = xr[8 * ii + j]; r[j] += v * v; }
        float nx2 = ((r[0] + r[1]) + (r[2] + r[3])) + ((r[4] + r[5]) + (r[6] + r[7]));

        // 16 codes per lane: dist = fl(fl(nx2+nc2) - 2*fl64->32(dot))
        unsigned long long m = ~0ull;
        const int kbase = lane * 16;
#pragma unroll 1
        for (int kk = 0; kk < 16; ++kk) {
            const int k = kbase + kk;
            const float* cp = cb + (size_t)k * D_;
            double acc = 0.0;
#pragma unroll
            for (int j = 0; j < D_; ++j)
                acc = fma((double)xr[j], (double)cp[j], acc);
            float dotf = (float)acc;
            float A    = nx2 + sc2[k];
            float dist = A - 2.0f * dotf;
            unsigned long long pk =
                ((unsigned long long)__float_as_uint(dist) << 32) | (unsigned)k;
            if (pk < m) m = pk;
        }
#pragma unroll
        for (int s = 32; s >= 1; s >>= 1) {
            unsigned long long o = __shfl_xor(m, s, 64);
            if (o < m) m = o;
        }
        const int gk = (int)(m & 0xFFFFFFFFull);

        if (gk != guess) {
            // patch zq row
            out[(size_t)b * D_ * TP_ + (size_t)lane * TP_ + tp] = cb[(size_t)gk * D_ + lane];
            // loss delta
            float xl = zp[(size_t)lane * TP_];
            float dn = xl - cb[(size_t)gk * D_ + lane];
            float dq = xl - cb[(size_t)guess * D_ + lane];
            float t  = dn * dn - dq * dq;
#pragma unroll
            for (int s = 32; s >= 1; s >>= 1) t += __shfl_xor(t, s, 64);
            if (lane == 0) {
                atomicAdd(ws + WS_LOSS, t);
                out[(size_t)N_ * D_ + n] = (float)gk;
                atomicSub(&gh[guess], 1u);
                atomicAdd(&gh[gk], 1u);
            }
        }
    }
}

// ---------------- finalize: scalars ----------------
__global__ void vq_fin(const float* __restrict__ ws, float* __restrict__ out) {
    __shared__ double red[K_];
    const int t = threadIdx.x;
    const unsigned* gh = reinterpret_cast<const unsigned*>(ws + WS_HIST);
    double p = (double)gh[t] * (1.0 / (double)N_);
    red[t] = -p * log(p + 1e-10);
    __syncthreads();
    for (int s = 512; s > 0; s >>= 1) {
        if (t < s) red[t] += red[t + s];
        __syncthreads();
    }
    if (t == 0) {
        out[(size_t)N_ * D_ + N_]     = BETA_ * ws[WS_LOSS] * (1.0f / (float)(N_ * D_));
        out[(size_t)N_ * D_ + N_ + 1] = (float)exp(red[0]);
    }
}

extern "C" void kernel_launch(void* const* d_in, const int* in_sizes, int n_in,
                              void* d_out, int out_size, void* d_ws, size_t ws_size,
                              hipStream_t stream) {
    const float* ze = (const float*)d_in[0];
    const float* cb = (const float*)d_in[1];
    float* out = (float*)d_out;
    float* ws  = (float*)d_ws;

    vq_init<<<dim3((K_ + 255) / 256), dim3(256), 0, stream>>>(cb, ws);
    vq_main<<<dim3(N_ / 256), dim3(256), 0, stream>>>(ze, cb, out, ws);
    vq_fix<<<dim3(64), dim3(256), 0, stream>>>(ze, cb, out, ws);
    vq_fin<<<dim3(1), dim3(K_), 0, stream>>>(ws, out);
}